// Round 10
// baseline (3451.248 us; speedup 1.0000x reference)
//
#include <hip/hip_runtime.h>
#include <math.h>

#define Ee   200
#define Hh   128
#define G4   512          // 4*H
#define Kk   24
#define Bb   64
#define Tt   1024
#define HIDd 256
#define NEGf (-10000.0f)

// ---------------------------------------------------------------------------
// K0: Wt[k][n] (k<200, n<1024): n<512 -> W_ih_f[n][k], else W_ih_b[n-512][k]
// ---------------------------------------------------------------------------
__global__ __launch_bounds__(256) void k_wt(const float* __restrict__ Wf,
                                            const float* __restrict__ Wb,
                                            float* __restrict__ Wt) {
    int idx = blockIdx.x * 256 + threadIdx.x;
    if (idx >= Ee * 1024) return;
    int k = idx >> 10, n = idx & 1023;
    Wt[idx] = (n < G4) ? Wf[n * Ee + k] : Wb[(n - G4) * Ee + k];
}

// ---------------------------------------------------------------------------
// K1: fused gather+GEMM, BM=128 BN=256 BK=8, register-prefetch double buffer.
//   (proven round 4)
// ---------------------------------------------------------------------------
__global__ __launch_bounds__(256, 2) void k_gemm2(const int* __restrict__ sent,
                                                  const float* __restrict__ emb,
                                                  const float* __restrict__ Wt,
                                                  float* __restrict__ Uc,
                                                  int c0T, int CT, int unified) {
    __shared__ float As[8][128];
    __shared__ float Bs[8][256];
    __shared__ int   toks[128];

    int tid = threadIdx.x;
    int n0  = blockIdx.x * 256;
    int m0  = blockIdx.y * 128;
    int dz  = blockIdx.z;
    int ty  = tid >> 4, tx = tid & 15;

    if (tid < 128) {
        int m = m0 + tid;
        int it = m >> 6, b = m & 63;
        int t = unified ? it : (dz ? (Tt - 1 - (c0T + it)) : (c0T + it));
        toks[tid] = sent[b * Tt + t];
    }
    __syncthreads();

    int am = tid & 127, ak4 = tid >> 7;
    int brow = tid >> 5, bc4 = tid & 31;

    const float* aptr = emb + (size_t)toks[am] * Ee + ak4 * 4;
    int bcol0 = (unified ? 0 : dz * G4) + n0;
    const float* bptr = Wt + (size_t)brow * 1024 + bcol0 + bc4 * 4;

    float acc[8][16];
#pragma unroll
    for (int i = 0; i < 8; ++i)
#pragma unroll
        for (int j = 0; j < 16; ++j) acc[i][j] = 0.f;

    float4 av  = *(const float4*)(aptr);
    float4 bv0 = *(const float4*)(bptr);
    float4 bv1 = *(const float4*)(bptr + 128);

    for (int kc = 0; kc < Ee; kc += 8) {
        As[ak4 * 4 + 0][am] = av.x;
        As[ak4 * 4 + 1][am] = av.y;
        As[ak4 * 4 + 2][am] = av.z;
        As[ak4 * 4 + 3][am] = av.w;
        *(float4*)&Bs[brow][bc4 * 4]       = bv0;
        *(float4*)&Bs[brow][128 + bc4 * 4] = bv1;
        __syncthreads();

        if (kc + 8 < Ee) {
            av  = *(const float4*)(aptr + kc + 8);
            bv0 = *(const float4*)(bptr + (size_t)(kc + 8) * 1024);
            bv1 = *(const float4*)(bptr + (size_t)(kc + 8) * 1024 + 128);
        }

#pragma unroll
        for (int k = 0; k < 8; ++k) {
            float a_[8], b_[16];
            *(float4*)&a_[0] = *(const float4*)&As[k][ty * 8];
            *(float4*)&a_[4] = *(const float4*)&As[k][ty * 8 + 4];
#pragma unroll
            for (int q = 0; q < 4; ++q)
                *(float4*)&b_[4 * q] = *(const float4*)&Bs[k][tx * 4 + 64 * q];
#pragma unroll
            for (int i = 0; i < 8; ++i)
#pragma unroll
                for (int j = 0; j < 16; ++j)
                    acc[i][j] = fmaf(a_[i], b_[j], acc[i][j]);
        }
        __syncthreads();
    }

    int dd   = unified ? (n0 >> 9) : dz;
    int ncol = unified ? (n0 & 511) : n0;
    float* base = Uc + (size_t)dd * ((size_t)CT * Bb * G4);
#pragma unroll
    for (int i = 0; i < 8; ++i) {
        float* dst = base + (size_t)(m0 + ty * 8 + i) * G4 + ncol + tx * 4;
#pragma unroll
        for (int q = 0; q < 4; ++q)
            *(float4*)(dst + 64 * q) = make_float4(acc[i][4 * q], acc[i][4 * q + 1],
                                                   acc[i][4 * q + 2], acc[i][4 * q + 3]);
    }
}

// ---------------------------------------------------------------------------
// K2: LSTM, shfl-butterfly reduce. 512 thr (8 waves), 2 barriers/step.
//   Wave w owns gate rows [64w,64w+64). Lane l: j8=l&7 col-chunk
//   [16*j8,16*j8+16), r8=l>>3 row-sub. Pass p -> row w*64+p*8+r8.
//   8 partials of a row live in 8 adjacent lanes -> 3x shfl_xor reduce
//   (same tree as v2's ps reduce; fp add commutative => bit-identical).
//   j8==0 lane: + (u + bias), activation (wave-uniform gate = w>>1),
//   write gsh[row]. No ps array, no third barrier. Tags: waves 0..2, one
//   extra pass, stored direct from registers.
// ---------------------------------------------------------------------------
__global__ __launch_bounds__(512, 1) void k_lstm5(const float* __restrict__ Uc,
                                                  const float* __restrict__ Whh_f,
                                                  const float* __restrict__ Whh_b,
                                                  const float* __restrict__ bih_f,
                                                  const float* __restrict__ bhh_f,
                                                  const float* __restrict__ bih_b,
                                                  const float* __restrict__ bhh_b,
                                                  const float* __restrict__ h0v,
                                                  const float* __restrict__ c0v,
                                                  const float* __restrict__ Wout,
                                                  float* __restrict__ hst,
                                                  float* __restrict__ cst,
                                                  float* __restrict__ pf,
                                                  int c0T, int CT, int first,
                                                  int unified) {
    __shared__ float hsh[Hh];
    __shared__ float gsh[G4];

    int tid  = threadIdx.x;
    int lane = tid & 63, w = tid >> 6;
    int j8 = lane & 7, r8 = lane >> 3;
    int b = blockIdx.x & 63, d = blockIdx.x >> 6;

    const float* Whh = d ? Whh_b : Whh_f;
    const float* bih = d ? bih_b : bih_f;
    const float* bhh = d ? bhh_b : bhh_f;

    // gate weights: rows w*64+p*8+r8, cols [16*j8,16*j8+16)
    float wreg[8][16];
#pragma unroll
    for (int p = 0; p < 8; ++p) {
        const float* wr = Whh + (size_t)(w * 64 + p * 8 + r8) * Hh + 16 * j8;
#pragma unroll
        for (int c4 = 0; c4 < 4; ++c4)
            *(float4*)&wreg[p][c4 * 4] = *(const float4*)(wr + c4 * 4);
    }
    // tag weights: waves 0..2, row kt = w*8+r8
    int kt = w * 8 + r8;
    float wt16[16];
    if (w < 3) {
        const float* wr = Wout + (size_t)kt * HIDd + d * Hh + 16 * j8;
#pragma unroll
        for (int c4 = 0; c4 < 4; ++c4)
            *(float4*)&wt16[c4 * 4] = *(const float4*)(wr + c4 * 4);
    }

    const float* Ub = Uc + (size_t)d * ((size_t)CT * Bb * G4);
    int u0 = unified ? (d ? (Tt - 1) : 0) : 0;
    int us = unified ? (d ? -1 : 1) : 1;

    float bias8[8], ucur8[8], unext8[8];
    if (j8 == 0) {
#pragma unroll
        for (int p = 0; p < 8; ++p) {
            int r = w * 64 + p * 8 + r8;
            bias8[p] = bih[r] + bhh[r];
            ucur8[p] = Ub[(size_t)u0 * (Bb * G4) + b * G4 + r];
        }
    }

    float cc = 0.f, hnew = 0.f;
    if (tid < Hh) {
        int si = (d * Bb + b) * Hh + tid;
        hnew = first ? h0v[si] : hst[si];
        cc   = first ? c0v[si] : cst[si];
        hsh[tid] = hnew;
    }
    __syncthreads();

    int t = u0;
    int gate = w >> 1;                 // wave-uniform: 0,0,1,1,2,2,3,3
    int rot  = j8 >> 1;                // bank-rotation for hv reads

    for (int i = 0; i <= CT; ++i) {
        int last = (i == CT);
        // ---- hv = h(i-1) cols [16*j8,16*j8+16), bank-rotated b128 reads ----
        float hv[16];
#pragma unroll
        for (int k = 0; k < 4; ++k) {
            int c4 = (k + rot) & 3;
            *(float4*)&hv[c4 * 4] = *(const float4*)&hsh[16 * j8 + 4 * c4];
        }

        // prefetch next-step u (hidden under the FMA passes)
        if (!last && j8 == 0 && i + 1 < CT) {
            const float* un = Ub + (size_t)(t + us) * (Bb * G4) + b * G4;
#pragma unroll
            for (int p = 0; p < 8; ++p) unext8[p] = un[w * 64 + p * 8 + r8];
        }

        // ---- tags (waves 0..2) from h(i-1), direct register store ----
        if (w < 3) {
            float s = 0.f;
#pragma unroll
            for (int c = 0; c < 16; ++c) s = fmaf(wt16[c], hv[c], s);
            s += __shfl_xor(s, 1);
            s += __shfl_xor(s, 2);
            s += __shfl_xor(s, 4);
            if (j8 == 0 && i >= 1) {
                int tp = c0T + i - 1;
                int tg = d ? (Tt - 1 - tp) : tp;
                pf[((size_t)(d * Bb + b) * Tt + tg) * Kk + kt] = s;
            }
        }

        // ---- gate passes: 16 FMA + butterfly + act -> gsh ----
        if (!last) {
#pragma unroll
            for (int p = 0; p < 8; ++p) {
                float s = 0.f;
#pragma unroll
                for (int c = 0; c < 16; ++c) s = fmaf(wreg[p][c], hv[c], s);
                s += __shfl_xor(s, 1);
                s += __shfl_xor(s, 2);
                s += __shfl_xor(s, 4);
                if (j8 == 0) {
                    float g = s + (ucur8[p] + bias8[p]);   // v2 association
                    gsh[w * 64 + p * 8 + r8] =
                        (gate == 2) ? tanhf(g) : 1.f / (1.f + expf(-g));
                }
            }
        }
        __syncthreads();

        // ---- cell (tid<128), wide, v2-identical ----
        if (!last) {
            if (tid < Hh) {
                float gi = gsh[tid], gf = gsh[Hh + tid];
                float gg = gsh[2 * Hh + tid], go = gsh[3 * Hh + tid];
                cc = gf * cc + gi * gg;
                hnew = go * tanhf(cc);
                hsh[tid] = hnew;
            }
            if (j8 == 0) {
#pragma unroll
                for (int p = 0; p < 8; ++p) ucur8[p] = unext8[p];
            }
            t += us;
        }
        __syncthreads();
    }

    if (tid < Hh) {
        int si = (d * Bb + b) * Hh + tid;
        hst[si] = hnew;
        cst[si] = cc;
    }
}

// ---------------------------------------------------------------------------
// K3: Viterbi, tree-argmax + 64-step LDS-staged feats (proven round 9, ~75us)
// ---------------------------------------------------------------------------
#define CMB(av, ai, bv_, bi_, ov, oi)                         \
    { bool g = (bv_) > (av); ov = g ? (bv_) : (av); oi = g ? (bi_) : (ai); }

__global__ __launch_bounds__(64) void k_viterbi(const float* __restrict__ pf,
                                                const float* __restrict__ bout,
                                                const float* __restrict__ trans,
                                                float* __restrict__ out) {
    __shared__ unsigned char bptr[Tt * Kk];
    __shared__ float fsh[2][64][25];
    __shared__ float tsh[Kk];
    __shared__ unsigned char path[Tt];

    int lane = threadIdx.x;
    int b    = blockIdx.x;
    int half   = (lane >= Kk) ? 1 : 0;
    int n      = half ? (lane - Kk) : lane;
    int active = (lane < 2 * Kk);

    float tr[12];
    float bo = 0.f;
    if (active) {
#pragma unroll
        for (int j = 0; j < 12; ++j) tr[j] = trans[n * Kk + half * 12 + j];
        bo = bout[n];
    }
    float v = (lane == 0) ? 0.f : NEGf;   // START=0

    const float* p0 = pf + (size_t)b * Tt * Kk;
    const float* p1 = pf + (size_t)(Bb + b) * Tt * Kk;

    float4 r0[6], r1[6];
#pragma unroll
    for (int j = 0; j < 6; ++j) {
        int f = 4 * (lane + 64 * j);
        r0[j] = *(const float4*)(p0 + f);
        r1[j] = *(const float4*)(p1 + f);
    }
#pragma unroll
    for (int j = 0; j < 6; ++j) {
        int f = 4 * (lane + 64 * j);
        int s = f / 24, k = f - 24 * s;
        fsh[0][s][k + 0] = r0[j].x + r1[j].x;
        fsh[0][s][k + 1] = r0[j].y + r1[j].y;
        fsh[0][s][k + 2] = r0[j].z + r1[j].z;
        fsh[0][s][k + 3] = r0[j].w + r1[j].w;
    }

    for (int c = 0; c < 16; ++c) {
        int cur = c & 1;
        if (c + 1 < 16) {
            const float* q0 = p0 + (c + 1) * 1536;
            const float* q1 = p1 + (c + 1) * 1536;
#pragma unroll
            for (int j = 0; j < 6; ++j) {
                int f = 4 * (lane + 64 * j);
                r0[j] = *(const float4*)(q0 + f);
                r1[j] = *(const float4*)(q1 + f);
            }
        }

        for (int s = 0; s < 64; ++s) {
            int t = c * 64 + s;
            if (active) {
                int pb = half * 12;
                float sc[12];
#pragma unroll
                for (int j = 0; j < 12; ++j) sc[j] = __shfl(v, pb + j) + tr[j];

                float l1v[6]; int l1i[6];
#pragma unroll
                for (int j = 0; j < 6; ++j)
                    CMB(sc[2 * j], 2 * j, sc[2 * j + 1], 2 * j + 1, l1v[j], l1i[j]);
                float l2v[3]; int l2i[3];
#pragma unroll
                for (int j = 0; j < 3; ++j)
                    CMB(l1v[2 * j], l1i[2 * j], l1v[2 * j + 1], l1i[2 * j + 1],
                        l2v[j], l2i[j]);
                float dv; int di;
                CMB(l2v[0], l2i[0], l2v[1], l2i[1], dv, di);
                float best; int bp;
                CMB(dv, di, l2v[2], l2i[2], best, bp);
                bp += pb;

                float ob  = __shfl(best, n + Kk);
                int   obp = __shfl(bp,   n + Kk);
                if (half == 0) {
                    if (ob > best) { best = ob; bp = obp; }
                    v = best + fsh[cur][s][n] + bo;
                    bptr[t * Kk + n] = (unsigned char)bp;
                }
            }
        }

        if (c + 1 < 16) {
#pragma unroll
            for (int j = 0; j < 6; ++j) {
                int f = 4 * (lane + 64 * j);
                int s = f / 24, k = f - 24 * s;
                fsh[cur ^ 1][s][k + 0] = r0[j].x + r1[j].x;
                fsh[cur ^ 1][s][k + 1] = r0[j].y + r1[j].y;
                fsh[cur ^ 1][s][k + 2] = r0[j].z + r1[j].z;
                fsh[cur ^ 1][s][k + 3] = r0[j].w + r1[j].w;
            }
        }
    }

    if (half == 0 && lane < Kk) tsh[n] = v + trans[1 * Kk + n];   // STOP=1
    __syncthreads();

    if (lane == 0) {
        float bestv = tsh[0];
        int tag = 0;
        for (int q = 1; q < Kk; ++q)
            if (tsh[q] > bestv) { bestv = tsh[q]; tag = q; }
        out[b] = bestv;
        for (int t = Tt - 1; t >= 1; --t) {
            path[t] = (unsigned char)tag;
            tag = bptr[t * Kk + tag];
        }
        path[0] = (unsigned char)tag;
    }
    __syncthreads();

    float* otag = out + Bb + (size_t)b * Tt;
    for (int t = lane; t < Tt; t += 64) otag[t] = (float)path[t];
}

// ---------------------------------------------------------------------------
// host launcher
// ---------------------------------------------------------------------------
extern "C" void kernel_launch(void* const* d_in, const int* in_sizes, int n_in,
                              void* d_out, int out_size, void* d_ws, size_t ws_size,
                              hipStream_t stream) {
    const int*   sent  = (const int*)d_in[0];
    const float* emb   = (const float*)d_in[2];
    const float* Wih_f = (const float*)d_in[3];
    const float* Whh_f = (const float*)d_in[4];
    const float* bih_f = (const float*)d_in[5];
    const float* bhh_f = (const float*)d_in[6];
    const float* Wih_b = (const float*)d_in[7];
    const float* Whh_b = (const float*)d_in[8];
    const float* bih_b = (const float*)d_in[9];
    const float* bhh_b = (const float*)d_in[10];
    const float* h0    = (const float*)d_in[11];
    const float* c0    = (const float*)d_in[12];
    const float* Wout  = (const float*)d_in[13];
    const float* bout  = (const float*)d_in[14];
    const float* trans = (const float*)d_in[15];

    float* ws  = (float*)d_ws;
    float* Wt  = ws;                       //   204,800 f
    float* pf  = Wt + 204800;              // 3,145,728 f
    float* hst = pf + 3145728;             //    16,384 f
    float* cst = hst + 16384;              //    16,384 f
    float* Uc  = cst + 16384;

    const size_t fixedf = 204800 + 3145728 + 16384 + 16384;
    size_t needU = (size_t)2 * Tt * Bb * G4;
    int unified = ((fixedf + needU) * 4 <= ws_size);

    k_wt<<<(Ee * 1024 + 255) / 256, 256, 0, stream>>>(Wih_f, Wih_b, Wt);

    if (unified) {
        k_gemm2<<<dim3(4, 512, 1), 256, 0, stream>>>(sent, emb, Wt, Uc, 0, Tt, 1);
        k_lstm5<<<128, 512, 0, stream>>>(Uc, Whh_f, Whh_b, bih_f, bhh_f,
                                         bih_b, bhh_b, h0, c0, Wout,
                                         hst, cst, pf, 0, Tt, 1, 1);
    } else {
        int CT = 64;
        const int cands[3] = {512, 256, 128};
        for (int ci = 0; ci < 3; ++ci)
            if ((fixedf + (size_t)2 * cands[ci] * Bb * G4) * 4 <= ws_size) {
                CT = cands[ci]; break;
            }
        int NC = Tt / CT;
        for (int cix = 0; cix < NC; ++cix) {
            k_gemm2<<<dim3(2, CT * 64 / 128, 2), 256, 0, stream>>>(
                sent, emb, Wt, Uc, cix * CT, CT, 0);
            k_lstm5<<<128, 512, 0, stream>>>(Uc, Whh_f, Whh_b, bih_f, bhh_f,
                                             bih_b, bhh_b, h0, c0, Wout,
                                             hst, cst, pf, cix * CT, CT,
                                             cix == 0, 0);
        }
    }

    k_viterbi<<<Bb, 64, 0, stream>>>(pf, bout, trans, (float*)d_out);
}

// Round 11
// 1516.549 us; speedup vs baseline: 2.2757x; 2.2757x over previous
//
#include <hip/hip_runtime.h>
#include <math.h>

#define Ee   200
#define Hh   128
#define G4   512          // 4*H
#define Kk   24
#define Bb   64
#define Tt   1024
#define HIDd 256
#define NEGf (-10000.0f)
#define PSTR 9            // partial-sum LDS stride (odd -> conflict-free)

// ---------------------------------------------------------------------------
// K0: Wt[k][n] (k<200, n<1024): n<512 -> W_ih_f[n][k], else W_ih_b[n-512][k]
// ---------------------------------------------------------------------------
__global__ __launch_bounds__(256) void k_wt(const float* __restrict__ Wf,
                                            const float* __restrict__ Wb,
                                            float* __restrict__ Wt) {
    int idx = blockIdx.x * 256 + threadIdx.x;
    if (idx >= Ee * 1024) return;
    int k = idx >> 10, n = idx & 1023;
    Wt[idx] = (n < G4) ? Wf[n * Ee + k] : Wb[(n - G4) * Ee + k];
}

// ---------------------------------------------------------------------------
// K1: fused gather+GEMM, BM=128 BN=256 BK=8, register-prefetch double buffer
//   (proven round 4/9/10).
// ---------------------------------------------------------------------------
__global__ __launch_bounds__(256, 2) void k_gemm2(const int* __restrict__ sent,
                                                  const float* __restrict__ emb,
                                                  const float* __restrict__ Wt,
                                                  float* __restrict__ Uc,
                                                  int c0T, int CT, int unified) {
    __shared__ float As[8][128];
    __shared__ float Bs[8][256];
    __shared__ int   toks[128];

    int tid = threadIdx.x;
    int n0  = blockIdx.x * 256;
    int m0  = blockIdx.y * 128;
    int dz  = blockIdx.z;
    int ty  = tid >> 4, tx = tid & 15;

    if (tid < 128) {
        int m = m0 + tid;
        int it = m >> 6, b = m & 63;
        int t = unified ? it : (dz ? (Tt - 1 - (c0T + it)) : (c0T + it));
        toks[tid] = sent[b * Tt + t];
    }
    __syncthreads();

    int am = tid & 127, ak4 = tid >> 7;
    int brow = tid >> 5, bc4 = tid & 31;

    const float* aptr = emb + (size_t)toks[am] * Ee + ak4 * 4;
    int bcol0 = (unified ? 0 : dz * G4) + n0;
    const float* bptr = Wt + (size_t)brow * 1024 + bcol0 + bc4 * 4;

    float acc[8][16];
#pragma unroll
    for (int i = 0; i < 8; ++i)
#pragma unroll
        for (int j = 0; j < 16; ++j) acc[i][j] = 0.f;

    float4 av  = *(const float4*)(aptr);
    float4 bv0 = *(const float4*)(bptr);
    float4 bv1 = *(const float4*)(bptr + 128);

    for (int kc = 0; kc < Ee; kc += 8) {
        As[ak4 * 4 + 0][am] = av.x;
        As[ak4 * 4 + 1][am] = av.y;
        As[ak4 * 4 + 2][am] = av.z;
        As[ak4 * 4 + 3][am] = av.w;
        *(float4*)&Bs[brow][bc4 * 4]       = bv0;
        *(float4*)&Bs[brow][128 + bc4 * 4] = bv1;
        __syncthreads();

        if (kc + 8 < Ee) {
            av  = *(const float4*)(aptr + kc + 8);
            bv0 = *(const float4*)(bptr + (size_t)(kc + 8) * 1024);
            bv1 = *(const float4*)(bptr + (size_t)(kc + 8) * 1024 + 128);
        }

#pragma unroll
        for (int k = 0; k < 8; ++k) {
            float a_[8], b_[16];
            *(float4*)&a_[0] = *(const float4*)&As[k][ty * 8];
            *(float4*)&a_[4] = *(const float4*)&As[k][ty * 8 + 4];
#pragma unroll
            for (int q = 0; q < 4; ++q)
                *(float4*)&b_[4 * q] = *(const float4*)&Bs[k][tx * 4 + 64 * q];
#pragma unroll
            for (int i = 0; i < 8; ++i)
#pragma unroll
                for (int j = 0; j < 16; ++j)
                    acc[i][j] = fmaf(a_[i], b_[j], acc[i][j]);
        }
        __syncthreads();
    }

    int dd   = unified ? (n0 >> 9) : dz;
    int ncol = unified ? (n0 & 511) : n0;
    float* base = Uc + (size_t)dd * ((size_t)CT * Bb * G4);
#pragma unroll
    for (int i = 0; i < 8; ++i) {
        float* dst = base + (size_t)(m0 + ty * 8 + i) * G4 + ncol + tx * 4;
#pragma unroll
        for (int q = 0; q < 4; ++q)
            *(float4*)(dst + 64 * q) = make_float4(acc[i][4 * q], acc[i][4 * q + 1],
                                                   acc[i][4 * q + 2], acc[i][4 * q + 3]);
    }
}

// ---------------------------------------------------------------------------
// K2: LSTM recurrence — EXACT round-3 k_lstm2 (proven 920us, conflicts=0).
//   128 blocks = (dir,b), 512 thr (8 waves). Wave w owns h-cols [16w,16w+16).
//   P1: partial dots -> ps   P2: reduce+u+bias+activation -> gsh
//   P3: cell (tid<128) + tag reduce/write of h(i-1) (tid 128..151).
// ---------------------------------------------------------------------------
__global__ __launch_bounds__(512, 2) void k_lstm2(const float* __restrict__ Uc,
                                                  const float* __restrict__ Whh_f,
                                                  const float* __restrict__ Whh_b,
                                                  const float* __restrict__ bih_f,
                                                  const float* __restrict__ bhh_f,
                                                  const float* __restrict__ bih_b,
                                                  const float* __restrict__ bhh_b,
                                                  const float* __restrict__ h0v,
                                                  const float* __restrict__ c0v,
                                                  const float* __restrict__ Wout,
                                                  float* __restrict__ hst,
                                                  float* __restrict__ cst,
                                                  float* __restrict__ pf,
                                                  int c0T, int CT, int first, int unified) {
    __shared__ float hsh[Hh];
    __shared__ float gsh[G4];
    __shared__ float ps[(G4 + Kk) * PSTR];

    int tid  = threadIdx.x;
    int lane = tid & 63, wv = tid >> 6;
    int b = blockIdx.x & 63, d = blockIdx.x >> 6;

    const float* Whh = d ? Whh_b : Whh_f;
    float bias = d ? (bih_b[tid] + bhh_b[tid]) : (bih_f[tid] + bhh_f[tid]);

    float w[8][16];
#pragma unroll
    for (int ri = 0; ri < 8; ++ri) {
        const float* wr = Whh + (size_t)(ri * 64 + lane) * Hh + wv * 16;
#pragma unroll
        for (int c4 = 0; c4 < 4; ++c4)
            *(float4*)&w[ri][c4 * 4] = *(const float4*)(wr + c4 * 4);
    }
    float wt[16];
    if (lane < Kk) {
        const float* wr = Wout + (size_t)lane * HIDd + d * Hh + wv * 16;
#pragma unroll
        for (int c4 = 0; c4 < 4; ++c4)
            *(float4*)&wt[c4 * 4] = *(const float4*)(wr + c4 * 4);
    }

    float cc = 0.f;
    if (tid < Hh) {
        int si = (d * Bb + b) * Hh + tid;
        hsh[tid] = first ? h0v[si] : hst[si];
        cc       = first ? c0v[si] : cst[si];
    }
    __syncthreads();

    const float* Ub = Uc + (size_t)d * ((size_t)CT * Bb * G4);
    int u0 = unified ? (d ? (Tt - 1) : 0) : 0;
    int us = unified ? (d ? -1 : 1) : 1;

    float ucur = Ub[(size_t)u0 * (Bb * G4) + b * G4 + tid];
    float unext = 0.f;

    for (int i = 0; i <= CT; ++i) {
        int last = (i == CT);
        // ---- P1: partial dots off current hsh = h(i-1) ----
        float hv[16];
        *(float4*)&hv[0]  = *(const float4*)&hsh[wv * 16];
        *(float4*)&hv[4]  = *(const float4*)&hsh[wv * 16 + 4];
        *(float4*)&hv[8]  = *(const float4*)&hsh[wv * 16 + 8];
        *(float4*)&hv[12] = *(const float4*)&hsh[wv * 16 + 12];

        if (lane < Kk) {
            float s = 0.f;
#pragma unroll
            for (int c = 0; c < 16; ++c) s = fmaf(wt[c], hv[c], s);
            ps[(G4 + lane) * PSTR + wv] = s;
        }
        if (!last) {
#pragma unroll
            for (int ri = 0; ri < 8; ++ri) {
                float s = 0.f;
#pragma unroll
                for (int c = 0; c < 16; ++c) s = fmaf(w[ri][c], hv[c], s);
                ps[(ri * 64 + lane) * PSTR + wv] = s;
            }
            if (i + 1 < CT)
                unext = Ub[(size_t)(u0 + (i + 1) * us) * (Bb * G4) + b * G4 + tid];
        }
        __syncthreads();

        // ---- P2: reduce + activate (thread tid owns gate tid) ----
        if (!last) {
            const float* pr = ps + (size_t)tid * PSTR;
            float s = ((pr[0] + pr[1]) + (pr[2] + pr[3])) +
                      ((pr[4] + pr[5]) + (pr[6] + pr[7]));
            s += ucur + bias;
            int gt = tid >> 7;                      // 0:i 1:f 2:g 3:o
            gsh[tid] = (gt == 2) ? tanhf(s) : 1.f / (1.f + expf(-s));
        }
        __syncthreads();

        // ---- P3: cell + tag emit of h(i-1) ----
        if (!last && tid < Hh) {
            float gi = gsh[tid], gf = gsh[Hh + tid];
            float gg = gsh[2 * Hh + tid], go = gsh[3 * Hh + tid];
            cc = gf * cc + gi * gg;
            hsh[tid] = go * tanhf(cc);
        }
        if (tid >= 128 && tid < 128 + Kk && i >= 1) {
            int k = tid - 128;
            const float* pr = ps + (size_t)(G4 + k) * PSTR;
            float s = ((pr[0] + pr[1]) + (pr[2] + pr[3])) +
                      ((pr[4] + pr[5]) + (pr[6] + pr[7]));
            int tp = c0T + i - 1;
            int tg = d ? (Tt - 1 - tp) : tp;
            pf[((size_t)(d * Bb + b) * Tt + tg) * Kk + k] = s;
        }
        __syncthreads();
        ucur = unext;
    }

    if (tid < Hh) {
        int si = (d * Bb + b) * Hh + tid;
        hst[si] = hsh[tid];
        cst[si] = cc;
    }
}

// ---------------------------------------------------------------------------
// K3: Viterbi, tree-argmax + 64-step LDS-staged feats (proven round 9, ~75us)
// ---------------------------------------------------------------------------
#define CMB(av, ai, bv_, bi_, ov, oi)                         \
    { bool g = (bv_) > (av); ov = g ? (bv_) : (av); oi = g ? (bi_) : (ai); }

__global__ __launch_bounds__(64) void k_viterbi(const float* __restrict__ pf,
                                                const float* __restrict__ bout,
                                                const float* __restrict__ trans,
                                                float* __restrict__ out) {
    __shared__ unsigned char bptr[Tt * Kk];
    __shared__ float fsh[2][64][25];
    __shared__ float tsh[Kk];
    __shared__ unsigned char path[Tt];

    int lane = threadIdx.x;
    int b    = blockIdx.x;
    int half   = (lane >= Kk) ? 1 : 0;
    int n      = half ? (lane - Kk) : lane;
    int active = (lane < 2 * Kk);

    float tr[12];
    float bo = 0.f;
    if (active) {
#pragma unroll
        for (int j = 0; j < 12; ++j) tr[j] = trans[n * Kk + half * 12 + j];
        bo = bout[n];
    }
    float v = (lane == 0) ? 0.f : NEGf;   // START=0

    const float* p0 = pf + (size_t)b * Tt * Kk;
    const float* p1 = pf + (size_t)(Bb + b) * Tt * Kk;

    float4 r0[6], r1[6];
#pragma unroll
    for (int j = 0; j < 6; ++j) {
        int f = 4 * (lane + 64 * j);
        r0[j] = *(const float4*)(p0 + f);
        r1[j] = *(const float4*)(p1 + f);
    }
#pragma unroll
    for (int j = 0; j < 6; ++j) {
        int f = 4 * (lane + 64 * j);
        int s = f / 24, k = f - 24 * s;
        fsh[0][s][k + 0] = r0[j].x + r1[j].x;
        fsh[0][s][k + 1] = r0[j].y + r1[j].y;
        fsh[0][s][k + 2] = r0[j].z + r1[j].z;
        fsh[0][s][k + 3] = r0[j].w + r1[j].w;
    }

    for (int c = 0; c < 16; ++c) {
        int cur = c & 1;
        if (c + 1 < 16) {
            const float* q0 = p0 + (c + 1) * 1536;
            const float* q1 = p1 + (c + 1) * 1536;
#pragma unroll
            for (int j = 0; j < 6; ++j) {
                int f = 4 * (lane + 64 * j);
                r0[j] = *(const float4*)(q0 + f);
                r1[j] = *(const float4*)(q1 + f);
            }
        }

        for (int s = 0; s < 64; ++s) {
            int t = c * 64 + s;
            if (active) {
                int pb = half * 12;
                float sc[12];
#pragma unroll
                for (int j = 0; j < 12; ++j) sc[j] = __shfl(v, pb + j) + tr[j];

                float l1v[6]; int l1i[6];
#pragma unroll
                for (int j = 0; j < 6; ++j)
                    CMB(sc[2 * j], 2 * j, sc[2 * j + 1], 2 * j + 1, l1v[j], l1i[j]);
                float l2v[3]; int l2i[3];
#pragma unroll
                for (int j = 0; j < 3; ++j)
                    CMB(l1v[2 * j], l1i[2 * j], l1v[2 * j + 1], l1i[2 * j + 1],
                        l2v[j], l2i[j]);
                float dv; int di;
                CMB(l2v[0], l2i[0], l2v[1], l2i[1], dv, di);
                float best; int bp;
                CMB(dv, di, l2v[2], l2i[2], best, bp);
                bp += pb;

                float ob  = __shfl(best, n + Kk);
                int   obp = __shfl(bp,   n + Kk);
                if (half == 0) {
                    if (ob > best) { best = ob; bp = obp; }
                    v = best + fsh[cur][s][n] + bo;
                    bptr[t * Kk + n] = (unsigned char)bp;
                }
            }
        }

        if (c + 1 < 16) {
#pragma unroll
            for (int j = 0; j < 6; ++j) {
                int f = 4 * (lane + 64 * j);
                int s = f / 24, k = f - 24 * s;
                fsh[cur ^ 1][s][k + 0] = r0[j].x + r1[j].x;
                fsh[cur ^ 1][s][k + 1] = r0[j].y + r1[j].y;
                fsh[cur ^ 1][s][k + 2] = r0[j].z + r1[j].z;
                fsh[cur ^ 1][s][k + 3] = r0[j].w + r1[j].w;
            }
        }
    }

    if (half == 0 && lane < Kk) tsh[n] = v + trans[1 * Kk + n];   // STOP=1
    __syncthreads();

    if (lane == 0) {
        float bestv = tsh[0];
        int tag = 0;
        for (int q = 1; q < Kk; ++q)
            if (tsh[q] > bestv) { bestv = tsh[q]; tag = q; }
        out[b] = bestv;
        for (int t = Tt - 1; t >= 1; --t) {
            path[t] = (unsigned char)tag;
            tag = bptr[t * Kk + tag];
        }
        path[0] = (unsigned char)tag;
    }
    __syncthreads();

    float* otag = out + Bb + (size_t)b * Tt;
    for (int t = lane; t < Tt; t += 64) otag[t] = (float)path[t];
}

// ---------------------------------------------------------------------------
// host launcher
// ---------------------------------------------------------------------------
extern "C" void kernel_launch(void* const* d_in, const int* in_sizes, int n_in,
                              void* d_out, int out_size, void* d_ws, size_t ws_size,
                              hipStream_t stream) {
    const int*   sent  = (const int*)d_in[0];
    const float* emb   = (const float*)d_in[2];
    const float* Wih_f = (const float*)d_in[3];
    const float* Whh_f = (const float*)d_in[4];
    const float* bih_f = (const float*)d_in[5];
    const float* bhh_f = (const float*)d_in[6];
    const float* Wih_b = (const float*)d_in[7];
    const float* Whh_b = (const float*)d_in[8];
    const float* bih_b = (const float*)d_in[9];
    const float* bhh_b = (const float*)d_in[10];
    const float* h0    = (const float*)d_in[11];
    const float* c0    = (const float*)d_in[12];
    const float* Wout  = (const float*)d_in[13];
    const float* bout  = (const float*)d_in[14];
    const float* trans = (const float*)d_in[15];

    float* ws  = (float*)d_ws;
    float* Wt  = ws;                       //   204,800 f
    float* pf  = Wt + 204800;              // 3,145,728 f
    float* hst = pf + 3145728;             //    16,384 f
    float* cst = hst + 16384;              //    16,384 f
    float* Uc  = cst + 16384;

    const size_t fixedf = 204800 + 3145728 + 16384 + 16384;
    size_t needU = (size_t)2 * Tt * Bb * G4;
    int unified = ((fixedf + needU) * 4 <= ws_size);

    k_wt<<<(Ee * 1024 + 255) / 256, 256, 0, stream>>>(Wih_f, Wih_b, Wt);

    if (unified) {
        k_gemm2<<<dim3(4, 512, 1), 256, 0, stream>>>(sent, emb, Wt, Uc, 0, Tt, 1);
        k_lstm2<<<128, 512, 0, stream>>>(Uc, Whh_f, Whh_b, bih_f, bhh_f,
                                         bih_b, bhh_b, h0, c0, Wout,
                                         hst, cst, pf, 0, Tt, 1, 1);
    } else {
        int CT = 64;
        const int cands[3] = {512, 256, 128};
        for (int ci = 0; ci < 3; ++ci)
            if ((fixedf + (size_t)2 * cands[ci] * Bb * G4) * 4 <= ws_size) {
                CT = cands[ci]; break;
            }
        int NC = Tt / CT;
        for (int cix = 0; cix < NC; ++cix) {
            k_gemm2<<<dim3(2, CT * 64 / 128, 2), 256, 0, stream>>>(
                sent, emb, Wt, Uc, cix * CT, CT, 0);
            k_lstm2<<<128, 512, 0, stream>>>(Uc, Whh_f, Whh_b, bih_f, bhh_f,
                                             bih_b, bhh_b, h0, c0, Wout,
                                             hst, cst, pf, cix * CT, CT,
                                             cix == 0, 0);
        }
    }

    k_viterbi<<<Bb, 64, 0, stream>>>(pf, bout, trans, (float*)d_out);
}